// Round 1
// baseline (2599.196 us; speedup 1.0000x reference)
//
#include <hip/hip_runtime.h>
#include <hip/hip_bf16.h>
#include <math.h>

#define N_NODES 100000
#define N_EDGES 1200000
#define KPRE    144            // 2*64 + 16
#define AVG_D   2.5649493574615367f
#define EPSV    1e-5f

// ---- workspace layout (bytes) ----
#define OFF_DEG       0u              // N u32
#define OFF_ROWLOCAL  400000u         // N u32
#define OFF_BSUM      800000u         // 512 u32
#define OFF_BOFFS     802048u         // 512 u32
#define OFF_ROWSTART  804096u         // N u32
#define OFF_CURSOR    1204096u        // N u32
#define OFF_EIDS      1604096u        // E u32
#define OFF_AB        6404096u        // N*2 f32
#define OFF_BNACC     7204096u        // 128 f32
#define OFF_BNFIN     7204608u        // 128 f32
#define OFF_AGG       7205120u        // N*256 f32
#define OFF_OUTPRE    109605120u      // N*64 f32  (end: 135205120)

__global__ void k_hist(const int* __restrict__ dst, unsigned* __restrict__ deg){
    int i = blockIdx.x*256 + threadIdx.x;
    if (i < N_EDGES) atomicAdd(&deg[dst[i]], 1u);
}

__global__ void k_scan1(const unsigned* __restrict__ deg, unsigned* __restrict__ rowlocal,
                        unsigned* __restrict__ bsum){
    __shared__ unsigned s[256];
    int t = threadIdx.x; int i = blockIdx.x*256 + t;
    unsigned d = (i < N_NODES) ? deg[i] : 0u;
    s[t] = d; __syncthreads();
    for (int off=1; off<256; off<<=1){
        unsigned v = (t>=off) ? s[t-off] : 0u; __syncthreads();
        s[t] += v; __syncthreads();
    }
    if (i < N_NODES) rowlocal[i] = s[t] - d;
    if (t == 255) bsum[blockIdx.x] = s[255];
}

__global__ void k_scan2(const unsigned* __restrict__ bsum, unsigned* __restrict__ boffs){
    __shared__ unsigned s[512];
    int t = threadIdx.x;
    unsigned v = (t < 391) ? bsum[t] : 0u;
    s[t] = v; __syncthreads();
    for (int off=1; off<512; off<<=1){
        unsigned x = (t>=off) ? s[t-off] : 0u; __syncthreads();
        s[t] += x; __syncthreads();
    }
    boffs[t] = s[t] - v;
}

__global__ void k_scan3(const unsigned* __restrict__ rowlocal, const unsigned* __restrict__ boffs,
                        unsigned* __restrict__ rowstart){
    int i = blockIdx.x*256 + threadIdx.x;
    if (i < N_NODES) rowstart[i] = rowlocal[i] + boffs[i>>8];
}

__global__ void k_scatter(const int* __restrict__ dst, const unsigned* __restrict__ rowstart,
                          unsigned* __restrict__ cursor, unsigned* __restrict__ eids){
    int i = blockIdx.x*256 + threadIdx.x;
    if (i < N_EDGES){
        int d = dst[i];
        unsigned pos = rowstart[d] + atomicAdd(&cursor[d], 1u);
        eids[pos] = (unsigned)i;
    }
}

// One wave per node: fused edge-MLP (z@W_pre+b_pre) + mean/max/min/std aggregation.
__global__ __launch_bounds__(256) void k_node(
    const float* __restrict__ h, const float* __restrict__ e_in,
    const float* __restrict__ W_pre, const float* __restrict__ b_pre,
    const unsigned* __restrict__ rowstart, const unsigned* __restrict__ deg,
    const unsigned* __restrict__ eids, const int* __restrict__ src,
    float* __restrict__ agg, float* __restrict__ ab)
{
    __shared__ __align__(16) float Wl[KPRE*64];      // 36.9 KB
    __shared__ __align__(16) float zbuf[4][2][160];  // wave-local z staging
    int tid = threadIdx.x;
    for (int i=tid; i<KPRE*64; i+=256) Wl[i] = W_pre[i];
    __syncthreads();
    int w = tid>>6, j = tid&63;
    int node = blockIdx.x*4 + w;          // grid=25000 -> exactly N
    if (node >= N_NODES) return;

    float bp = b_pre[j];
    unsigned start = rowstart[node];
    int d = (int)deg[node];
    float hd = h[node*64 + j];
    float* zA = zbuf[w][0]; float* zB = zbuf[w][1];
    zA[64+j] = hd; zB[64+j] = hd;        // dst part is loop-invariant

    float s1=0.f, s2=0.f, mx=-INFINITY, mn=INFINITY;
    for (int i=0; i<d; i+=2){
        unsigned eA = eids[start+i];
        bool hasB = (i+1 < d);
        unsigned eB = hasB ? eids[start+i+1] : eA;
        int sA = src[eA], sB = src[eB];
        zA[j] = h[sA*64 + j];
        zB[j] = h[sB*64 + j];
        if (j < 16){ zA[128+j] = e_in[eA*16 + j]; zB[128+j] = e_in[eB*16 + j]; }
        // wave-local LDS RAW: compiler inserts lgkmcnt, no barrier needed
        float a0=0,a1=0,a2=0,a3=0,b0=0,b1=0,b2=0,b3=0;
        #pragma unroll 6
        for (int k4=0; k4<36; k4++){
            float4 za = *(const float4*)&zA[k4*4];   // broadcast b128
            float4 zb = *(const float4*)&zB[k4*4];
            const float* wr = &Wl[k4*256 + j];       // row-contiguous: conflict-free
            float w0=wr[0], w1=wr[64], w2=wr[128], w3=wr[192];
            a0=fmaf(za.x,w0,a0); b0=fmaf(zb.x,w0,b0);
            a1=fmaf(za.y,w1,a1); b1=fmaf(zb.y,w1,b1);
            a2=fmaf(za.z,w2,a2); b2=fmaf(zb.z,w2,b2);
            a3=fmaf(za.w,w3,a3); b3=fmaf(zb.w,w3,b3);
        }
        float mA = (a0+a1)+(a2+a3) + bp;
        s1 += mA; s2 = fmaf(mA,mA,s2); mx = fmaxf(mx,mA); mn = fminf(mn,mA);
        if (hasB){
            float mB = (b0+b1)+(b2+b3) + bp;
            s1 += mB; s2 = fmaf(mB,mB,s2); mx = fmaxf(mx,mB); mn = fminf(mn,mB);
        }
    }
    float D = (float)d;
    float mean = s1/D;
    float var  = fmaxf(s2/D - mean*mean, 0.f);
    float sd   = sqrtf(var + EPSV);
    float logd = logf(D + 1.f);
    float* ag = agg + (size_t)node*256;
    ag[j] = mean; ag[64+j] = mx; ag[128+j] = mn; ag[192+j] = sd;
    if (j == 0){
        ab[node*2+0] = logd / AVG_D;
        ab[node*2+1] = AVG_D / logd;
    }
}

// out_pre = [h|agg|a*agg|b*agg] @ W_post + b_post, *snorm; block = 32 nodes, 4 waves x 8 nodes
__global__ __launch_bounds__(256) void k_gemm(
    const float* __restrict__ h, const float* __restrict__ agg,
    const float* __restrict__ ab, const float* __restrict__ snorm,
    const float* __restrict__ W_post, const float* __restrict__ b_post,
    float* __restrict__ out_pre, float* __restrict__ bn_acc)
{
    __shared__ __align__(16) float fs[32*320];   // [h(64)|agg(256)] per node, 40 KB
    __shared__ __align__(16) float Wl2[64*64];   // W_post chunk, 16 KB
    __shared__ float sa[32], sb[32], sn[32];
    __shared__ float bnred[2][4][64];
    int tid = threadIdx.x;
    int base = blockIdx.x*32;                    // grid=3125 -> exactly N
    for (int i=tid; i<32*320; i+=256){
        int n = i/320, q = i - n*320;
        int gn = base + n;
        fs[i] = (q < 64) ? h[gn*64 + q] : agg[(size_t)gn*256 + (q-64)];
    }
    if (tid < 32){
        sa[tid] = ab[(base+tid)*2];
        sb[tid] = ab[(base+tid)*2+1];
        sn[tid] = snorm[base+tid];
    }
    int wv = tid>>6, c = tid&63;
    float acc0[8]={0,0,0,0,0,0,0,0}, acc1[8]={0,0,0,0,0,0,0,0};
    float acc2[8]={0,0,0,0,0,0,0,0}, acc3[8]={0,0,0,0,0,0,0,0};

    auto chunk = [&](int cch, float* acc, int fsofs){
        __syncthreads();
        const float* Wg = W_post + cch*4096;
        for (int i=tid; i<4096; i+=256) Wl2[i] = Wg[i];
        __syncthreads();
        int kbase = cch*64 + fsofs;
        const float* fw = &fs[wv*8*320 + kbase];
        #pragma unroll
        for (int u4=0; u4<16; u4++){
            float w0 = Wl2[u4*256 +       c];
            float w1 = Wl2[u4*256 +  64 + c];
            float w2 = Wl2[u4*256 + 128 + c];
            float w3 = Wl2[u4*256 + 192 + c];
            #pragma unroll
            for (int n=0; n<8; n++){
                float4 fv = *(const float4*)&fw[n*320 + u4*4];   // broadcast b128
                acc[n] = fmaf(fv.x,w0,acc[n]); acc[n] = fmaf(fv.y,w1,acc[n]);
                acc[n] = fmaf(fv.z,w2,acc[n]); acc[n] = fmaf(fv.w,w3,acc[n]);
            }
        }
    };
    chunk(0, acc0, 0);                              // h     rows 0..63
    for (int cc=1; cc<=4; cc++) chunk(cc, acc1, 0);    // agg   rows 64..319
    for (int cc=5; cc<=8; cc++) chunk(cc, acc2, -256); // a*agg rows 320..575
    for (int cc=9; cc<=12; cc++) chunk(cc, acc3, -512);// b*agg rows 576..831

    float bs=0.f, bq=0.f;
    float bpc = b_post[c];
    #pragma unroll
    for (int n=0; n<8; n++){
        int ln = wv*8 + n; int gn = base + ln;
        float v = acc0[n] + acc1[n] + sa[ln]*acc2[n] + sb[ln]*acc3[n] + bpc;
        v *= sn[ln];
        out_pre[(size_t)gn*64 + c] = v;
        bs += v; bq = fmaf(v,v,bq);
    }
    bnred[0][wv][c] = bs; bnred[1][wv][c] = bq;
    __syncthreads();
    if (wv == 0){
        float s = bnred[0][0][c]+bnred[0][1][c]+bnred[0][2][c]+bnred[0][3][c];
        float q = bnred[1][0][c]+bnred[1][1][c]+bnred[1][2][c]+bnred[1][3][c];
        atomicAdd(&bn_acc[c], s);
        atomicAdd(&bn_acc[64+c], q);
    }
}

__global__ void k_bnfin(const float* __restrict__ bn_acc, const float* __restrict__ gamma,
                        const float* __restrict__ beta, float* __restrict__ bn_fin){
    int c = threadIdx.x;
    float invN = 1.f/(float)N_NODES;
    float mu = bn_acc[c]*invN;
    float ms = bn_acc[64+c]*invN;
    float var = fmaxf(ms - mu*mu, 0.f);
    float scale = gamma[c] / sqrtf(var + 1e-5f);
    bn_fin[c] = scale;
    bn_fin[64+c] = beta[c] - mu*scale;
}

__global__ void k_apply(const float* __restrict__ out_pre, const float* __restrict__ bn_fin,
                        float* __restrict__ out){
    int i = blockIdx.x*256 + threadIdx.x;     // float4 index; grid covers N*16 exactly
    int c4 = (i & 15) * 4;
    float4 v  = ((const float4*)out_pre)[i];
    float4 sc = *(const float4*)&bn_fin[c4];
    float4 sh = *(const float4*)&bn_fin[64 + c4];
    float4 o;
    o.x = fmaf(v.x, sc.x, sh.x); o.y = fmaf(v.y, sc.y, sh.y);
    o.z = fmaf(v.z, sc.z, sh.z); o.w = fmaf(v.w, sc.w, sh.w);
    ((float4*)out)[i] = o;
}

extern "C" void kernel_launch(void* const* d_in, const int* in_sizes, int n_in,
                              void* d_out, int out_size, void* d_ws, size_t ws_size,
                              hipStream_t stream)
{
    const float* h      = (const float*)d_in[0];
    const float* e_in   = (const float*)d_in[1];
    const float* snorm  = (const float*)d_in[2];
    const float* W_pre  = (const float*)d_in[3];
    const float* b_pre  = (const float*)d_in[4];
    const float* W_post = (const float*)d_in[5];
    const float* b_post = (const float*)d_in[6];
    const float* gamma  = (const float*)d_in[7];
    const float* beta   = (const float*)d_in[8];
    const int*   src    = (const int*)d_in[9];
    const int*   dst    = (const int*)d_in[10];

    char* ws = (char*)d_ws;
    unsigned* deg      = (unsigned*)(ws + OFF_DEG);
    unsigned* rowlocal = (unsigned*)(ws + OFF_ROWLOCAL);
    unsigned* bsum     = (unsigned*)(ws + OFF_BSUM);
    unsigned* boffs    = (unsigned*)(ws + OFF_BOFFS);
    unsigned* rowstart = (unsigned*)(ws + OFF_ROWSTART);
    unsigned* cursor   = (unsigned*)(ws + OFF_CURSOR);
    unsigned* eids     = (unsigned*)(ws + OFF_EIDS);
    float*    abuf     = (float*)(ws + OFF_AB);
    float*    bnacc    = (float*)(ws + OFF_BNACC);
    float*    bnfin    = (float*)(ws + OFF_BNFIN);
    float*    aggp     = (float*)(ws + OFF_AGG);
    float*    outpre   = (float*)(ws + OFF_OUTPRE);

    hipMemsetAsync(ws + OFF_DEG,    0, 400000, stream);
    hipMemsetAsync(ws + OFF_CURSOR, 0, 400000, stream);
    hipMemsetAsync(ws + OFF_BNACC,  0, 512,    stream);

    k_hist   <<<4688, 256, 0, stream>>>(dst, deg);
    k_scan1  <<<391,  256, 0, stream>>>(deg, rowlocal, bsum);
    k_scan2  <<<1,    512, 0, stream>>>(bsum, boffs);
    k_scan3  <<<391,  256, 0, stream>>>(rowlocal, boffs, rowstart);
    k_scatter<<<4688, 256, 0, stream>>>(dst, rowstart, cursor, eids);
    k_node   <<<25000,256, 0, stream>>>(h, e_in, W_pre, b_pre, rowstart, deg, eids, src, aggp, abuf);
    k_gemm   <<<3125, 256, 0, stream>>>(h, aggp, abuf, snorm, W_post, b_post, outpre, bnacc);
    k_bnfin  <<<1,    64,  0, stream>>>(bnacc, gamma, beta, bnfin);
    k_apply  <<<6250, 256, 0, stream>>>(outpre, bnfin, (float*)d_out);
}

// Round 2
// 668.466 us; speedup vs baseline: 3.8883x; 3.8883x over previous
//
#include <hip/hip_runtime.h>
#include <hip/hip_bf16.h>
#include <math.h>

#define N_NODES 100000
#define N_EDGES 1200000
#define NT_EDGE 75000      // edge tiles of 16 (16*75000 == E exactly)
#define NT_POST 6250       // node tiles of 16 (16*6250 == N exactly)
#define AVG_D   2.5649493574615367f
#define EPSV    1e-5f

typedef __attribute__((ext_vector_type(8))) short short8;
typedef __attribute__((ext_vector_type(4))) float f32x4;

// ---- workspace layout (bytes), total 135,205,120 (== round-1 proven size) ----
#define OFF_DEG       0u
#define OFF_ROWLOCAL  400000u
#define OFF_BSUM      800000u
#define OFF_BOFFS     802048u
#define OFF_ROWSTART  804096u
#define OFF_CURSOR    1204096u
#define OFF_EIDS      1604096u
#define OFF_AB        6404096u        // N*2 f32
#define OFF_BNACC     7204096u        // 128 f32
#define OFF_BNFIN     7204608u        // 128 f32
#define OFF_MBUF      7205120u        // E*32 bf16 = 76.8 MB (one channel-half)
#define OFF_AGG       84005120u       // N*256 bf16 = 51.2 MB
#define OFF_OUTPRE    OFF_MBUF        // N*64 f32 = 25.6 MB, aliases mbuf (dead by then)

__device__ __forceinline__ short f2b(float f){          // fp32 -> bf16 bits (RNE)
    union { float f; unsigned u; } c; c.f = f;
    unsigned u = c.u;
    unsigned r = (u + 0x7fffu + ((u >> 16) & 1u)) >> 16;
    return (short)r;
}
__device__ __forceinline__ float b2f(unsigned short u){ // bf16 bits -> fp32
    union { unsigned u; float f; } c; c.u = ((unsigned)u) << 16;
    return c.f;
}

// ================= CSR build (unchanged from round 1) =================
__global__ void k_hist(const int* __restrict__ dst, unsigned* __restrict__ deg){
    int i = blockIdx.x*256 + threadIdx.x;
    if (i < N_EDGES) atomicAdd(&deg[dst[i]], 1u);
}
__global__ void k_scan1(const unsigned* __restrict__ deg, unsigned* __restrict__ rowlocal,
                        unsigned* __restrict__ bsum){
    __shared__ unsigned s[256];
    int t = threadIdx.x; int i = blockIdx.x*256 + t;
    unsigned d = (i < N_NODES) ? deg[i] : 0u;
    s[t] = d; __syncthreads();
    for (int off=1; off<256; off<<=1){
        unsigned v = (t>=off) ? s[t-off] : 0u; __syncthreads();
        s[t] += v; __syncthreads();
    }
    if (i < N_NODES) rowlocal[i] = s[t] - d;
    if (t == 255) bsum[blockIdx.x] = s[255];
}
__global__ void k_scan2(const unsigned* __restrict__ bsum, unsigned* __restrict__ boffs){
    __shared__ unsigned s[512];
    int t = threadIdx.x;
    unsigned v = (t < 391) ? bsum[t] : 0u;
    s[t] = v; __syncthreads();
    for (int off=1; off<512; off<<=1){
        unsigned x = (t>=off) ? s[t-off] : 0u; __syncthreads();
        s[t] += x; __syncthreads();
    }
    boffs[t] = s[t] - v;
}
__global__ void k_scan3(const unsigned* __restrict__ rowlocal, const unsigned* __restrict__ boffs,
                        unsigned* __restrict__ rowstart){
    int i = blockIdx.x*256 + threadIdx.x;
    if (i < N_NODES) rowstart[i] = rowlocal[i] + boffs[i>>8];
}
__global__ void k_scatter(const int* __restrict__ dst, const unsigned* __restrict__ rowstart,
                          unsigned* __restrict__ cursor, unsigned* __restrict__ eids){
    int i = blockIdx.x*256 + threadIdx.x;
    if (i < N_EDGES){
        int d = dst[i];
        unsigned pos = rowstart[d] + atomicAdd(&cursor[d], 1u);
        eids[pos] = (unsigned)i;
    }
}

// ================= edge GEMM via MFMA: m = [h[src]|h[dst]|e] @ W_pre + b_pre =================
// One 16-edge tile per wave-iteration; wave covers 32 output cols (chalf selects which 32).
__global__ __launch_bounds__(256) void k_edge(
    const float* __restrict__ h, const float* __restrict__ e_in,
    const float* __restrict__ W_pre, const float* __restrict__ b_pre,
    const unsigned* __restrict__ eids, const int* __restrict__ src,
    const int* __restrict__ dst, unsigned short* __restrict__ mbuf, int chalf)
{
    int tid = threadIdx.x;
    int wv = tid>>6, l = tid&63;
    int lr = l&15, lg = l>>4;

    // B-frags: W_pre zero-padded to K=160 rows; B[k][col]: col=lr+16cg+32chalf, k=32ks+8lg+e
    short8 B[5][2];
    #pragma unroll
    for (int ks=0; ks<5; ks++){
        #pragma unroll
        for (int cg=0; cg<2; cg++){
            int col = chalf*32 + cg*16 + lr;
            short8 b;
            #pragma unroll
            for (int e=0; e<8; e++){
                int k = ks*32 + lg*8 + e;
                float w = (k < 144) ? W_pre[k*64 + col] : 0.f;
                b[e] = f2b(w);
            }
            B[ks][cg] = b;
        }
    }
    float bias0 = b_pre[chalf*32 + lr];
    float bias1 = b_pre[chalf*32 + 16 + lr];

    int gw = blockIdx.x*4 + wv;
    int nw = gridDim.x*4;
    for (int t = gw; t < NT_EDGE; t += nw){
        unsigned eid = eids[t*16 + lr];          // A row = lr (lane&15)
        int sn = src[eid], dn = dst[eid];
        const float* hs = h + (size_t)sn*64 + lg*8;
        const float* hd = h + (size_t)dn*64 + lg*8;
        const float* zp[4] = { hs, hs + 32, hd, hd + 32 };
        f32x4 acc0 = {0.f,0.f,0.f,0.f};
        f32x4 acc1 = {0.f,0.f,0.f,0.f};
        #pragma unroll
        for (int ks=0; ks<4; ks++){
            float4 u0 = *(const float4*)(zp[ks]);
            float4 u1 = *(const float4*)(zp[ks] + 4);
            short8 A;
            A[0]=f2b(u0.x); A[1]=f2b(u0.y); A[2]=f2b(u0.z); A[3]=f2b(u0.w);
            A[4]=f2b(u1.x); A[5]=f2b(u1.y); A[6]=f2b(u1.z); A[7]=f2b(u1.w);
            acc0 = __builtin_amdgcn_mfma_f32_16x16x32_bf16(A, B[ks][0], acc0, 0,0,0);
            acc1 = __builtin_amdgcn_mfma_f32_16x16x32_bf16(A, B[ks][1], acc1, 0,0,0);
        }
        {   // ks=4: e (k 128..143) + zero pad (144..159)
            short8 A = {0,0,0,0,0,0,0,0};
            if (lg < 2){
                const float* pe = e_in + (size_t)eid*16 + lg*8;
                float4 u0 = *(const float4*)(pe);
                float4 u1 = *(const float4*)(pe + 4);
                A[0]=f2b(u0.x); A[1]=f2b(u0.y); A[2]=f2b(u0.z); A[3]=f2b(u0.w);
                A[4]=f2b(u1.x); A[5]=f2b(u1.y); A[6]=f2b(u1.z); A[7]=f2b(u1.w);
            }
            acc0 = __builtin_amdgcn_mfma_f32_16x16x32_bf16(A, B[4][0], acc0, 0,0,0);
            acc1 = __builtin_amdgcn_mfma_f32_16x16x32_bf16(A, B[4][1], acc1, 0,0,0);
        }
        // D: row = 4*lg + r, col = lr (+16 for acc1); store bf16, CSR row order
        #pragma unroll
        for (int r=0; r<4; r++){
            size_t row = (size_t)t*16 + lg*4 + r;
            mbuf[row*32 + lr]      = (unsigned short)f2b(acc0[r] + bias0);
            mbuf[row*32 + 16 + lr] = (unsigned short)f2b(acc1[r] + bias1);
        }
    }
}

// ================= segment aggregation: mean/max/min/std over CSR rows =================
__global__ __launch_bounds__(256) void k_agg(
    const unsigned short* __restrict__ mbuf, const unsigned* __restrict__ rowstart,
    const unsigned* __restrict__ deg, unsigned short* __restrict__ agg,
    float* __restrict__ ab, int chalf)
{
    int wv = threadIdx.x>>6, l = threadIdx.x&63;
    int node = blockIdx.x*4 + wv;                 // grid 25000*4 == N exactly
    int hf = l>>5, ch = l&31;
    unsigned start = rowstart[node];
    int d = (int)deg[node];                       // d >= 1 always (dst includes arange(N))
    const unsigned short* p = mbuf + (size_t)start*32 + ch;
    float s1=0.f, s2=0.f, mx=-3.4e38f, mn=3.4e38f;
    for (int i=hf; i<d; i+=2){                    // lanes 0-31: even rows, 32-63: odd rows
        float v = b2f(p[(size_t)i*32]);
        s1 += v; s2 = fmaf(v,v,s2);
        mx = fmaxf(mx,v); mn = fminf(mn,v);
    }
    s1 += __shfl_xor(s1,32); s2 += __shfl_xor(s2,32);
    mx = fmaxf(mx, __shfl_xor(mx,32)); mn = fminf(mn, __shfl_xor(mn,32));
    float D = (float)d;
    float mean = s1/D;
    float sd = sqrtf(fmaxf(s2/D - mean*mean, 0.f) + EPSV);
    if (l < 32){
        size_t o = (size_t)node*256 + chalf*32 + ch;
        agg[o]       = (unsigned short)f2b(mean);
        agg[o + 64]  = (unsigned short)f2b(mx);
        agg[o + 128] = (unsigned short)f2b(mn);
        agg[o + 192] = (unsigned short)f2b(sd);
    }
    if (l == 0 && chalf == 0){
        float logd = logf(D + 1.f);
        ab[node*2]   = logd / AVG_D;
        ab[node*2+1] = AVG_D / logd;
    }
}

// ================= post GEMM via MFMA: out = [h|agg]@Wm + a*(agg@W2) + b*(agg@W3) =================
// Wave = one 16-col group (4 waves cover 64 cols); block strides over node tiles.
__global__ __launch_bounds__(256) void k_post(
    const float* __restrict__ h, const unsigned short* __restrict__ agg,
    const float* __restrict__ ab, const float* __restrict__ snorm,
    const float* __restrict__ W_post, const float* __restrict__ b_post,
    float* __restrict__ out_pre, float* __restrict__ bn_acc)
{
    int tid = threadIdx.x;
    int cg = tid>>6;
    int l = tid&63, lr = l&15, lg = l>>4;
    int col = cg*16 + lr;

    short8 Bm[10], B2[8], B3[8];
    #pragma unroll
    for (int ks=0; ks<10; ks++){
        short8 b;
        #pragma unroll
        for (int e=0; e<8; e++){
            int row = ks*32 + lg*8 + e;           // rows 0..319: [h(64) | agg(256)]
            b[e] = f2b(W_post[row*64 + col]);
        }
        Bm[ks] = b;
    }
    #pragma unroll
    for (int ks=0; ks<8; ks++){
        short8 b, c;
        #pragma unroll
        for (int e=0; e<8; e++){
            int row = ks*32 + lg*8 + e;
            b[e] = f2b(W_post[(320+row)*64 + col]);   // a*agg block
            c[e] = f2b(W_post[(576+row)*64 + col]);   // b*agg block
        }
        B2[ks] = b; B3[ks] = c;
    }
    float bias = b_post[col];
    float bs = 0.f, bq = 0.f;

    for (int t = blockIdx.x; t < NT_POST; t += gridDim.x){
        int nodeA = t*16 + lr;                    // A row = lane&15
        f32x4 aM = {0.f,0.f,0.f,0.f}, a2 = {0.f,0.f,0.f,0.f}, a3 = {0.f,0.f,0.f,0.f};
        #pragma unroll
        for (int ks=0; ks<2; ks++){               // h part (fp32 -> bf16)
            const float* p = h + (size_t)nodeA*64 + ks*32 + lg*8;
            float4 u0 = *(const float4*)p, u1 = *(const float4*)(p+4);
            short8 A;
            A[0]=f2b(u0.x); A[1]=f2b(u0.y); A[2]=f2b(u0.z); A[3]=f2b(u0.w);
            A[4]=f2b(u1.x); A[5]=f2b(u1.y); A[6]=f2b(u1.z); A[7]=f2b(u1.w);
            aM = __builtin_amdgcn_mfma_f32_16x16x32_bf16(A, Bm[ks], aM, 0,0,0);
        }
        #pragma unroll
        for (int ks=0; ks<8; ks++){               // agg part (already bf16: direct 16B load)
            short8 A = *(const short8*)(agg + (size_t)nodeA*256 + ks*32 + lg*8);
            aM = __builtin_amdgcn_mfma_f32_16x16x32_bf16(A, Bm[2+ks], aM, 0,0,0);
            a2 = __builtin_amdgcn_mfma_f32_16x16x32_bf16(A, B2[ks],  a2, 0,0,0);
            a3 = __builtin_amdgcn_mfma_f32_16x16x32_bf16(A, B3[ks],  a3, 0,0,0);
        }
        #pragma unroll
        for (int r=0; r<4; r++){
            int node = t*16 + lg*4 + r;           // D row = 4*lg + r
            float av = ab[node*2], bv = ab[node*2+1];
            float v = (aM[r] + av*a2[r] + bv*a3[r] + bias) * snorm[node];
            out_pre[(size_t)node*64 + col] = v;
            bs += v; bq = fmaf(v,v,bq);
        }
    }
    // fold rows: lanes {l, l^16, l^32, l^48} share the same col
    bs += __shfl_xor(bs, 16); bs += __shfl_xor(bs, 32);
    bq += __shfl_xor(bq, 16); bq += __shfl_xor(bq, 32);
    if (l < 16){
        atomicAdd(&bn_acc[cg*16 + l], bs);
        atomicAdd(&bn_acc[64 + cg*16 + l], bq);
    }
}

// ================= BatchNorm finalize + apply =================
__global__ void k_bnfin(const float* __restrict__ bn_acc, const float* __restrict__ gamma,
                        const float* __restrict__ beta, float* __restrict__ bn_fin){
    int c = threadIdx.x;
    float invN = 1.f/(float)N_NODES;
    float mu = bn_acc[c]*invN;
    float ms = bn_acc[64+c]*invN;
    float var = fmaxf(ms - mu*mu, 0.f);
    float scale = gamma[c] / sqrtf(var + 1e-5f);
    bn_fin[c] = scale;
    bn_fin[64+c] = beta[c] - mu*scale;
}
__global__ void k_apply(const float* __restrict__ out_pre, const float* __restrict__ bn_fin,
                        float* __restrict__ out){
    int i = blockIdx.x*256 + threadIdx.x;     // float4 index; 6250*256*4 == N*64 exactly
    int c4 = (i & 15) * 4;
    float4 v  = ((const float4*)out_pre)[i];
    float4 sc = *(const float4*)&bn_fin[c4];
    float4 sh = *(const float4*)&bn_fin[64 + c4];
    float4 o;
    o.x = fmaf(v.x, sc.x, sh.x); o.y = fmaf(v.y, sc.y, sh.y);
    o.z = fmaf(v.z, sc.z, sh.z); o.w = fmaf(v.w, sc.w, sh.w);
    ((float4*)out)[i] = o;
}

extern "C" void kernel_launch(void* const* d_in, const int* in_sizes, int n_in,
                              void* d_out, int out_size, void* d_ws, size_t ws_size,
                              hipStream_t stream)
{
    const float* h      = (const float*)d_in[0];
    const float* e_in   = (const float*)d_in[1];
    const float* snorm  = (const float*)d_in[2];
    const float* W_pre  = (const float*)d_in[3];
    const float* b_pre  = (const float*)d_in[4];
    const float* W_post = (const float*)d_in[5];
    const float* b_post = (const float*)d_in[6];
    const float* gamma  = (const float*)d_in[7];
    const float* beta   = (const float*)d_in[8];
    const int*   src    = (const int*)d_in[9];
    const int*   dst    = (const int*)d_in[10];

    char* ws = (char*)d_ws;
    unsigned* deg      = (unsigned*)(ws + OFF_DEG);
    unsigned* rowlocal = (unsigned*)(ws + OFF_ROWLOCAL);
    unsigned* bsum     = (unsigned*)(ws + OFF_BSUM);
    unsigned* boffs    = (unsigned*)(ws + OFF_BOFFS);
    unsigned* rowstart = (unsigned*)(ws + OFF_ROWSTART);
    unsigned* cursor   = (unsigned*)(ws + OFF_CURSOR);
    unsigned* eids     = (unsigned*)(ws + OFF_EIDS);
    float*    abuf     = (float*)(ws + OFF_AB);
    float*    bnacc    = (float*)(ws + OFF_BNACC);
    float*    bnfin    = (float*)(ws + OFF_BNFIN);
    unsigned short* mbuf = (unsigned short*)(ws + OFF_MBUF);
    unsigned short* aggp = (unsigned short*)(ws + OFF_AGG);
    float*    outpre   = (float*)(ws + OFF_OUTPRE);

    hipMemsetAsync(ws + OFF_DEG,    0, 400000, stream);
    hipMemsetAsync(ws + OFF_CURSOR, 0, 400000, stream);
    hipMemsetAsync(ws + OFF_BNACC,  0, 512,    stream);

    k_hist   <<<4688, 256, 0, stream>>>(dst, deg);
    k_scan1  <<<391,  256, 0, stream>>>(deg, rowlocal, bsum);
    k_scan2  <<<1,    512, 0, stream>>>(bsum, boffs);
    k_scan3  <<<391,  256, 0, stream>>>(rowlocal, boffs, rowstart);
    k_scatter<<<4688, 256, 0, stream>>>(dst, rowstart, cursor, eids);

    k_edge   <<<1024, 256, 0, stream>>>(h, e_in, W_pre, b_pre, eids, src, dst, mbuf, 0);
    k_agg    <<<25000,256, 0, stream>>>(mbuf, rowstart, deg, aggp, abuf, 0);
    k_edge   <<<1024, 256, 0, stream>>>(h, e_in, W_pre, b_pre, eids, src, dst, mbuf, 1);
    k_agg    <<<25000,256, 0, stream>>>(mbuf, rowstart, deg, aggp, abuf, 1);

    k_post   <<<512,  256, 0, stream>>>(h, aggp, abuf, snorm, W_post, b_post, outpre, bnacc);
    k_bnfin  <<<1,    64,  0, stream>>>(bnacc, gamma, beta, bnfin);
    k_apply  <<<6250, 256, 0, stream>>>(outpre, bnfin, (float*)d_out);
}

// Round 3
// 593.109 us; speedup vs baseline: 4.3823x; 1.1271x over previous
//
#include <hip/hip_runtime.h>
#include <hip/hip_bf16.h>
#include <math.h>

#define N_NODES 100000
#define N_EDGES 1200000
#define NT_EDGE 75000          // total 16-edge tiles
#define NPASS   3
#define TILES_PER_PASS 25000   // NT_EDGE / NPASS
#define ROWS_PER_PASS  400000  // TILES_PER_PASS * 16
#define NT_POST 6250           // node tiles of 16
#define AVG_D   2.5649493574615367f
#define EPSV    1e-5f

typedef __attribute__((ext_vector_type(8))) short short8;
typedef __attribute__((ext_vector_type(4))) float f32x4;

// ---- workspace layout (bytes), total 122,405,120 (< 135,205,120 proven) ----
#define OFF_DEG       0u
#define OFF_ROWLOCAL  400000u
#define OFF_BSUM      800000u         // 2048; dead after scans -> reused as CARRY
#define OFF_BOFFS     802048u         // 2048
#define OFF_ROWSTART  804096u
#define OFF_CURSOR    1204096u
#define OFF_EIDS      1604096u        // E u32
#define OFF_AB        6404096u        // N*2 f32
#define OFF_BNACC     7204096u        // 128 f32
#define OFF_BNFIN     7204608u        // 128 f32
#define OFF_HB        7205120u        // N*64 bf16 = 12.8 MB
#define OFF_MBUF      20005120u       // 400000 rows * 64 bf16 = 51.2 MB
#define OFF_AGG       71205120u       // N*256 bf16 = 51.2 MB  (end 122,405,120)
#define OFF_CARRY     OFF_BSUM        // 2 splits * 4 stats * 64 f32 = 2048 B
#define OFF_OUTPRE    OFF_MBUF        // N*64 f32 = 25.6 MB, mbuf dead by k_post

__device__ __forceinline__ short f2b(float f){          // fp32 -> bf16 bits (RNE)
    union { float f; unsigned u; } c; c.f = f;
    unsigned u = c.u;
    unsigned r = (u + 0x7fffu + ((u >> 16) & 1u)) >> 16;
    return (short)r;
}
__device__ __forceinline__ float b2f(unsigned u16){     // bf16 bits (low 16) -> fp32
    union { unsigned u; float f; } c; c.u = u16 << 16;
    return c.f;
}
__device__ __forceinline__ unsigned pk(float a, float b){
    return ((unsigned)(unsigned short)f2b(a)) | (((unsigned)(unsigned short)f2b(b)) << 16);
}

// ================= CSR build + h->bf16 conversion =================
__global__ void k_prep(const int* __restrict__ dst, unsigned* __restrict__ deg,
                       const float* __restrict__ h, unsigned short* __restrict__ hb){
    int i = blockIdx.x*256 + threadIdx.x;
    if (i < N_EDGES) atomicAdd(&deg[dst[i]], 1u);
    if (i < 800000){                                    // 8 floats per thread
        const float4* p = (const float4*)h + (size_t)i*2;
        float4 u0 = p[0], u1 = p[1];
        uint4 o;
        o.x = pk(u0.x,u0.y); o.y = pk(u0.z,u0.w);
        o.z = pk(u1.x,u1.y); o.w = pk(u1.z,u1.w);
        ((uint4*)hb)[i] = o;
    }
}
__global__ void k_scan1(const unsigned* __restrict__ deg, unsigned* __restrict__ rowlocal,
                        unsigned* __restrict__ bsum){
    __shared__ unsigned s[256];
    int t = threadIdx.x; int i = blockIdx.x*256 + t;
    unsigned d = (i < N_NODES) ? deg[i] : 0u;
    s[t] = d; __syncthreads();
    for (int off=1; off<256; off<<=1){
        unsigned v = (t>=off) ? s[t-off] : 0u; __syncthreads();
        s[t] += v; __syncthreads();
    }
    if (i < N_NODES) rowlocal[i] = s[t] - d;
    if (t == 255) bsum[blockIdx.x] = s[255];
}
__global__ void k_scan2(const unsigned* __restrict__ bsum, unsigned* __restrict__ boffs){
    __shared__ unsigned s[512];
    int t = threadIdx.x;
    unsigned v = (t < 391) ? bsum[t] : 0u;
    s[t] = v; __syncthreads();
    for (int off=1; off<512; off<<=1){
        unsigned x = (t>=off) ? s[t-off] : 0u; __syncthreads();
        s[t] += x; __syncthreads();
    }
    boffs[t] = s[t] - v;
}
__global__ void k_scan3(const unsigned* __restrict__ rowlocal, const unsigned* __restrict__ boffs,
                        unsigned* __restrict__ rowstart){
    int i = blockIdx.x*256 + threadIdx.x;
    if (i < N_NODES) rowstart[i] = rowlocal[i] + boffs[i>>8];
}
__global__ void k_scatter(const int* __restrict__ dst, const unsigned* __restrict__ rowstart,
                          unsigned* __restrict__ cursor, unsigned* __restrict__ eids){
    int i = blockIdx.x*256 + threadIdx.x;
    if (i < N_EDGES){
        int d = dst[i];
        unsigned pos = rowstart[d] + atomicAdd(&cursor[d], 1u);
        eids[pos] = (unsigned)i;
    }
}

// ================= edge GEMM via MFMA, all 64 cols, one edge-range pass =================
__global__ __launch_bounds__(256) void k_edge(
    const unsigned short* __restrict__ hb, const float* __restrict__ e_in,
    const float* __restrict__ W_pre, const float* __restrict__ b_pre,
    const unsigned* __restrict__ eids, const int* __restrict__ src,
    const int* __restrict__ dst, unsigned short* __restrict__ mbuf, int pass)
{
    int tid = threadIdx.x;
    int wv = tid>>6, l = tid&63;
    int lr = l&15, lg = l>>4;

    // B-frags: B[k][col], col = cg*16+lr, k = 32*ks + 8*lg + e  (K padded 144->160)
    short8 B[5][4];
    #pragma unroll
    for (int ks=0; ks<5; ks++){
        #pragma unroll
        for (int cg=0; cg<4; cg++){
            short8 b;
            #pragma unroll
            for (int e=0; e<8; e++){
                int k = ks*32 + lg*8 + e;
                b[e] = (k < 144) ? f2b(W_pre[k*64 + cg*16 + lr]) : (short)0;
            }
            B[ks][cg] = b;
        }
    }
    float bias[4];
    #pragma unroll
    for (int cg=0; cg<4; cg++) bias[cg] = b_pre[cg*16 + lr];

    int t0 = pass*TILES_PER_PASS;
    int gw = blockIdx.x*4 + wv;
    int nw = gridDim.x*4;
    for (int t = gw; t < TILES_PER_PASS; t += nw){
        int gt = t0 + t;
        unsigned eid = eids[gt*16 + lr];        // A row = lr
        int sn = src[eid], dn = dst[eid];
        const unsigned short* ps = hb + (size_t)sn*64 + lg*8;
        const unsigned short* pd = hb + (size_t)dn*64 + lg*8;
        f32x4 acc[4];
        #pragma unroll
        for (int cg=0; cg<4; cg++) acc[cg] = (f32x4){0.f,0.f,0.f,0.f};

        short8 A;
        A = *(const short8*)ps;                 // ks0: h[src] cols 0..31
        #pragma unroll
        for (int cg=0; cg<4; cg++) acc[cg] = __builtin_amdgcn_mfma_f32_16x16x32_bf16(A, B[0][cg], acc[cg], 0,0,0);
        A = *(const short8*)(ps + 32);          // ks1: h[src] cols 32..63
        #pragma unroll
        for (int cg=0; cg<4; cg++) acc[cg] = __builtin_amdgcn_mfma_f32_16x16x32_bf16(A, B[1][cg], acc[cg], 0,0,0);
        A = *(const short8*)pd;                 // ks2: h[dst] cols 0..31
        #pragma unroll
        for (int cg=0; cg<4; cg++) acc[cg] = __builtin_amdgcn_mfma_f32_16x16x32_bf16(A, B[2][cg], acc[cg], 0,0,0);
        A = *(const short8*)(pd + 32);          // ks3: h[dst] cols 32..63
        #pragma unroll
        for (int cg=0; cg<4; cg++) acc[cg] = __builtin_amdgcn_mfma_f32_16x16x32_bf16(A, B[3][cg], acc[cg], 0,0,0);
        {                                       // ks4: e (k 128..143) + pad
            short8 A4 = {0,0,0,0,0,0,0,0};
            if (lg < 2){
                const float* pe = e_in + (size_t)eid*16 + lg*8;
                float4 u0 = *(const float4*)pe, u1 = *(const float4*)(pe+4);
                A4[0]=f2b(u0.x); A4[1]=f2b(u0.y); A4[2]=f2b(u0.z); A4[3]=f2b(u0.w);
                A4[4]=f2b(u1.x); A4[5]=f2b(u1.y); A4[6]=f2b(u1.z); A4[7]=f2b(u1.w);
            }
            #pragma unroll
            for (int cg=0; cg<4; cg++) acc[cg] = __builtin_amdgcn_mfma_f32_16x16x32_bf16(A4, B[4][cg], acc[cg], 0,0,0);
        }
        // D: row = 4*lg + r (local to pass), col = cg*16 + lr
        #pragma unroll
        for (int r=0; r<4; r++){
            size_t row = (size_t)t*16 + lg*4 + r;
            #pragma unroll
            for (int cg=0; cg<4; cg++)
                mbuf[row*64 + cg*16 + lr] = (unsigned short)f2b(acc[cg][r] + bias[cg]);
        }
    }
}

// ================= segment aggregation over CSR rows (pass-windowed, carry at splits) ====
__global__ __launch_bounds__(256) void k_agg(
    const unsigned short* __restrict__ mbuf, const unsigned* __restrict__ rowstart,
    const unsigned* __restrict__ deg, unsigned short* __restrict__ agg,
    float* __restrict__ ab, float* __restrict__ carry, int pass)
{
    int wv = threadIdx.x>>6, l = threadIdx.x&63;
    int node = blockIdx.x*4 + wv;                 // grid 25000*4 == N
    int hf = l>>5, c = l&31;                      // lane c handles cols 2c, 2c+1
    unsigned start = rowstart[node];
    int d = (int)deg[node];                       // d >= 1 (dst includes arange(N))
    unsigned end = start + (unsigned)d;
    unsigned lo = (unsigned)pass * ROWS_PER_PASS;
    unsigned hi = lo + ROWS_PER_PASS;
    if (end <= lo || start >= hi) return;
    unsigned a = start < lo ? lo : start;
    unsigned b = end > hi ? hi : end;
    int n = (int)(b - a);
    const unsigned short* p = mbuf + (size_t)(a - lo)*64 + 2*c;
    float s1a=0.f,s2a=0.f,mxa=-3.402823466e38f,mna=3.402823466e38f;
    float s1b=0.f,s2b=0.f,mxb=-3.402823466e38f,mnb=3.402823466e38f;
    for (int i=hf; i<n; i+=2){                    // 2 rows in flight, 256 B/wave-iter
        unsigned v = *(const unsigned*)(p + (size_t)i*64);
        float va = b2f(v & 0xffffu), vb = b2f(v >> 16);
        s1a += va; s2a = fmaf(va,va,s2a); mxa = fmaxf(mxa,va); mna = fminf(mna,va);
        s1b += vb; s2b = fmaf(vb,vb,s2b); mxb = fmaxf(mxb,vb); mnb = fminf(mnb,vb);
    }
    s1a += __shfl_xor(s1a,32); s2a += __shfl_xor(s2a,32);
    mxa = fmaxf(mxa,__shfl_xor(mxa,32)); mna = fminf(mna,__shfl_xor(mna,32));
    s1b += __shfl_xor(s1b,32); s2b += __shfl_xor(s2b,32);
    mxb = fmaxf(mxb,__shfl_xor(mxb,32)); mnb = fminf(mnb,__shfl_xor(mnb,32));
    if (l < 32){
        if (start < lo){                          // merge carry from split (pass-1)
            const float* cb = carry + (size_t)(pass-1)*256;
            s1a += cb[      2*c];   s1b += cb[      2*c+1];
            s2a += cb[ 64 + 2*c];   s2b += cb[ 64 + 2*c+1];
            mxa = fmaxf(mxa, cb[128 + 2*c]); mxb = fmaxf(mxb, cb[128 + 2*c+1]);
            mna = fminf(mna, cb[192 + 2*c]); mnb = fminf(mnb, cb[192 + 2*c+1]);
        }
        if (end > hi){                            // spill partial to carry[pass]
            float* cb = carry + (size_t)pass*256;
            cb[      2*c] = s1a;  cb[      2*c+1] = s1b;
            cb[ 64 + 2*c] = s2a;  cb[ 64 + 2*c+1] = s2b;
            cb[128 + 2*c] = mxa;  cb[128 + 2*c+1] = mxb;
            cb[192 + 2*c] = mna;  cb[192 + 2*c+1] = mnb;
        } else {                                  // finalize
            float D = (float)d;
            float meana = s1a/D, meanb = s1b/D;
            float sda = sqrtf(fmaxf(s2a/D - meana*meana, 0.f) + EPSV);
            float sdb = sqrtf(fmaxf(s2b/D - meanb*meanb, 0.f) + EPSV);
            unsigned* ag = (unsigned*)(agg + (size_t)node*256) + c;  // packed col pair
            ag[ 0] = pk(meana, meanb);
            ag[32] = pk(mxa,  mxb);
            ag[64] = pk(mna,  mnb);
            ag[96] = pk(sda,  sdb);
            if (c == 0){
                float logd = logf(D + 1.f);
                ab[node*2]   = logd / AVG_D;
                ab[node*2+1] = AVG_D / logd;
            }
        }
    }
}

// ================= post GEMM via MFMA: out = [h|agg]@Wm + a*(agg@W2) + b*(agg@W3) =========
__global__ __launch_bounds__(256) void k_post(
    const unsigned short* __restrict__ hb, const unsigned short* __restrict__ agg,
    const float* __restrict__ ab, const float* __restrict__ snorm,
    const float* __restrict__ W_post, const float* __restrict__ b_post,
    float* __restrict__ out_pre, float* __restrict__ bn_acc)
{
    int tid = threadIdx.x;
    int cg = tid>>6;
    int l = tid&63, lr = l&15, lg = l>>4;
    int col = cg*16 + lr;

    short8 Bm[10], B2[8], B3[8];
    #pragma unroll
    for (int ks=0; ks<10; ks++){
        short8 b;
        #pragma unroll
        for (int e=0; e<8; e++){
            int row = ks*32 + lg*8 + e;           // rows 0..319: [h(64) | agg(256)]
            b[e] = f2b(W_post[row*64 + col]);
        }
        Bm[ks] = b;
    }
    #pragma unroll
    for (int ks=0; ks<8; ks++){
        short8 b, c;
        #pragma unroll
        for (int e=0; e<8; e++){
            int row = ks*32 + lg*8 + e;
            b[e] = f2b(W_post[(320+row)*64 + col]);   // a*agg block
            c[e] = f2b(W_post[(576+row)*64 + col]);   // b*agg block
        }
        B2[ks] = b; B3[ks] = c;
    }
    float bias = b_post[col];
    float bs = 0.f, bq = 0.f;

    for (int t = blockIdx.x; t < NT_POST; t += gridDim.x){
        int nodeA = t*16 + lr;                    // A row = lane&15
        f32x4 aM = {0.f,0.f,0.f,0.f}, a2 = {0.f,0.f,0.f,0.f}, a3 = {0.f,0.f,0.f,0.f};
        #pragma unroll
        for (int ks=0; ks<2; ks++){               // h part: direct bf16 load
            short8 A = *(const short8*)(hb + (size_t)nodeA*64 + ks*32 + lg*8);
            aM = __builtin_amdgcn_mfma_f32_16x16x32_bf16(A, Bm[ks], aM, 0,0,0);
        }
        #pragma unroll
        for (int ks=0; ks<8; ks++){               // agg part
            short8 A = *(const short8*)(agg + (size_t)nodeA*256 + ks*32 + lg*8);
            aM = __builtin_amdgcn_mfma_f32_16x16x32_bf16(A, Bm[2+ks], aM, 0,0,0);
            a2 = __builtin_amdgcn_mfma_f32_16x16x32_bf16(A, B2[ks],  a2, 0,0,0);
            a3 = __builtin_amdgcn_mfma_f32_16x16x32_bf16(A, B3[ks],  a3, 0,0,0);
        }
        #pragma unroll
        for (int r=0; r<4; r++){
            int node = t*16 + lg*4 + r;           // D row = 4*lg + r
            float av = ab[node*2], bv = ab[node*2+1];
            float v = (aM[r] + av*a2[r] + bv*a3[r] + bias) * snorm[node];
            out_pre[(size_t)node*64 + col] = v;
            bs += v; bq = fmaf(v,v,bq);
        }
    }
    bs += __shfl_xor(bs, 16); bs += __shfl_xor(bs, 32);
    bq += __shfl_xor(bq, 16); bq += __shfl_xor(bq, 32);
    if (l < 16){
        atomicAdd(&bn_acc[cg*16 + l], bs);
        atomicAdd(&bn_acc[64 + cg*16 + l], bq);
    }
}

// ================= BatchNorm finalize + apply =================
__global__ void k_bnfin(const float* __restrict__ bn_acc, const float* __restrict__ gamma,
                        const float* __restrict__ beta, float* __restrict__ bn_fin){
    int c = threadIdx.x;
    float invN = 1.f/(float)N_NODES;
    float mu = bn_acc[c]*invN;
    float ms = bn_acc[64+c]*invN;
    float var = fmaxf(ms - mu*mu, 0.f);
    float scale = gamma[c] / sqrtf(var + 1e-5f);
    bn_fin[c] = scale;
    bn_fin[64+c] = beta[c] - mu*scale;
}
__global__ void k_apply(const float* __restrict__ out_pre, const float* __restrict__ bn_fin,
                        float* __restrict__ out){
    int i = blockIdx.x*256 + threadIdx.x;     // float4 index; 6250*256*4 == N*64
    int c4 = (i & 15) * 4;
    float4 v  = ((const float4*)out_pre)[i];
    float4 sc = *(const float4*)&bn_fin[c4];
    float4 sh = *(const float4*)&bn_fin[64 + c4];
    float4 o;
    o.x = fmaf(v.x, sc.x, sh.x); o.y = fmaf(v.y, sc.y, sh.y);
    o.z = fmaf(v.z, sc.z, sh.z); o.w = fmaf(v.w, sc.w, sh.w);
    ((float4*)out)[i] = o;
}

extern "C" void kernel_launch(void* const* d_in, const int* in_sizes, int n_in,
                              void* d_out, int out_size, void* d_ws, size_t ws_size,
                              hipStream_t stream)
{
    const float* h      = (const float*)d_in[0];
    const float* e_in   = (const float*)d_in[1];
    const float* snorm  = (const float*)d_in[2];
    const float* W_pre  = (const float*)d_in[3];
    const float* b_pre  = (const float*)d_in[4];
    const float* W_post = (const float*)d_in[5];
    const float* b_post = (const float*)d_in[6];
    const float* gamma  = (const float*)d_in[7];
    const float* beta   = (const float*)d_in[8];
    const int*   src    = (const int*)d_in[9];
    const int*   dst    = (const int*)d_in[10];

    char* ws = (char*)d_ws;
    unsigned* deg      = (unsigned*)(ws + OFF_DEG);
    unsigned* rowlocal = (unsigned*)(ws + OFF_ROWLOCAL);
    unsigned* bsum     = (unsigned*)(ws + OFF_BSUM);
    unsigned* boffs    = (unsigned*)(ws + OFF_BOFFS);
    unsigned* rowstart = (unsigned*)(ws + OFF_ROWSTART);
    unsigned* cursor   = (unsigned*)(ws + OFF_CURSOR);
    unsigned* eids     = (unsigned*)(ws + OFF_EIDS);
    float*    abuf     = (float*)(ws + OFF_AB);
    float*    bnacc    = (float*)(ws + OFF_BNACC);
    float*    bnfin    = (float*)(ws + OFF_BNFIN);
    unsigned short* hb   = (unsigned short*)(ws + OFF_HB);
    unsigned short* mbuf = (unsigned short*)(ws + OFF_MBUF);
    unsigned short* aggp = (unsigned short*)(ws + OFF_AGG);
    float*    carry    = (float*)(ws + OFF_CARRY);
    float*    outpre   = (float*)(ws + OFF_OUTPRE);

    hipMemsetAsync(ws + OFF_DEG,    0, 400000, stream);
    hipMemsetAsync(ws + OFF_CURSOR, 0, 400000, stream);
    hipMemsetAsync(ws + OFF_BNACC,  0, 512,    stream);

    k_prep   <<<4688, 256, 0, stream>>>(dst, deg, h, hb);
    k_scan1  <<<391,  256, 0, stream>>>(deg, rowlocal, bsum);
    k_scan2  <<<1,    512, 0, stream>>>(bsum, boffs);
    k_scan3  <<<391,  256, 0, stream>>>(rowlocal, boffs, rowstart);
    k_scatter<<<4688, 256, 0, stream>>>(dst, rowstart, cursor, eids);

    for (int pass = 0; pass < NPASS; pass++){
        k_edge <<<1024, 256, 0, stream>>>(hb, e_in, W_pre, b_pre, eids, src, dst, mbuf, pass);
        k_agg  <<<25000,256, 0, stream>>>(mbuf, rowstart, deg, aggp, abuf, carry, pass);
    }

    k_post   <<<512,  256, 0, stream>>>(hb, aggp, abuf, snorm, W_post, b_post, outpre, bnacc);
    k_bnfin  <<<1,    64,  0, stream>>>(bnacc, gamma, beta, bnfin);
    k_apply  <<<6250, 256, 0, stream>>>(outpre, bnfin, (float*)d_out);
}